// Round 1
// baseline (169.525 us; speedup 1.0000x reference)
//
#include <hip/hip_runtime.h>

#define C 64
#define T 262144
#define K 8
#define L 256
#define B (T / L)      // 1024 time blocks
#define TT 64          // LDS chunk (time steps per staging round)
#define LDS_STRIDE 65  // +1 pad: banks (r + t) % 32 -> 2-way only (free)

// One cascade time-step. Y1/Y2 are the y1/y2 register arrays for this parity,
// U1/U2 the section-0 input history. Writes new y1 into Y2 slots (rotation),
// new u1 into U2 slot. All t-terms read only OLD state (computed before any
// commit), then an 8-deep fma chain through b0, then commits.
#define STEP(Y1, Y2, U1, U2, XIN)                                            \
  {                                                                          \
    float tkv[K];                                                            \
    tkv[0] = fmaf(b1c[0], U1,                                                \
             fmaf(b2c[0], U2, fmaf(na1[0], Y1[0], na2[0] * Y2[0])));         \
    _Pragma("unroll")                                                        \
    for (int k = 1; k < K; ++k)                                              \
      tkv[k] = fmaf(b1c[k], Y1[k - 1],                                       \
               fmaf(b2c[k], Y2[k - 1],                                       \
               fmaf(na1[k], Y1[k], na2[k] * Y2[k])));                        \
    float o = fmaf(b0c[0], (XIN), tkv[0]);                                   \
    U2 = (XIN);                                                              \
    _Pragma("unroll")                                                        \
    for (int k = 1; k < K; ++k) {                                            \
      float o2 = fmaf(b0c[k], o, tkv[k]);                                    \
      Y2[k - 1] = o;                                                         \
      o = o2;                                                                \
    }                                                                        \
    Y2[K - 1] = o;                                                           \
    lastout = o;                                                             \
  }

// PHASE 1: run each time-block from zero y-state, record end state z[b].
// PHASE 3: run each time-block from z[b-1], write output.
// One wave per block; lane = channel. Global<->LDS transpose for coalescing.
template <int PHASE>
__global__ __launch_bounds__(64) void sos_kernel(
    const float* __restrict__ x, const float* __restrict__ sos,
    const float* __restrict__ sx, const float* __restrict__ sy,
    float* __restrict__ z, float* __restrict__ out) {
  __shared__ float lds[64 * LDS_STRIDE];
  const int b = blockIdx.x;
  const int lane = threadIdx.x;  // = channel

  // Coefficients (wave-uniform -> scalar regs). sos row: b0,b1,b2,1,a1,a2
  float b0c[K], b1c[K], b2c[K], na1[K], na2[K];
#pragma unroll
  for (int k = 0; k < K; ++k) {
    b0c[k] = sos[k * 6 + 0];
    b1c[k] = sos[k * 6 + 1];
    b2c[k] = sos[k * 6 + 2];
    na1[k] = -sos[k * 6 + 4];
    na2[k] = -sos[k * 6 + 5];
  }

  // State: yA/yB rotate roles (y1/y2) each step; uA/uB = section-0 x history.
  float yA[K], yB[K], uA, uB;
  if (b == 0) {
    uA = sx[lane * 2 + 0];  // state_x[0][c][0] = x lag1
    uB = sx[lane * 2 + 1];  // x lag2
#pragma unroll
    for (int k = 0; k < K; ++k) {
      yA[k] = sy[(k * 64 + lane) * 2 + 0];
      yB[k] = sy[(k * 64 + lane) * 2 + 1];
    }
  } else {
    const int t0 = b * L;
    uA = x[(size_t)lane * T + t0 - 1];  // true x history (known input)
    uB = x[(size_t)lane * T + t0 - 2];
    if (PHASE == 1) {
#pragma unroll
      for (int k = 0; k < K; ++k) {
        yA[k] = 0.f;
        yB[k] = 0.f;
      }
    } else {
#pragma unroll
      for (int k = 0; k < K; ++k) {
        yA[k] = z[((b - 1) * 16 + k) * 64 + lane];
        yB[k] = z[((b - 1) * 16 + 8 + k) * 64 + lane];
      }
    }
  }

  float lastout = 0.f;
  for (int ch = 0; ch < L / TT; ++ch) {
    const int t0 = b * L + ch * TT;
    __syncthreads();  // prior chunk's LDS reads done before overwrite
    // Coalesced stage-in: row r (channel), lanes sweep time.
#pragma unroll
    for (int r = 0; r < 64; ++r)
      lds[r * LDS_STRIDE + lane] = x[(size_t)r * T + t0 + lane];
    __syncthreads();
#pragma unroll 2
    for (int t = 0; t < TT; t += 2) {
      float xin = lds[lane * LDS_STRIDE + t];
      STEP(yA, yB, uA, uB, xin)
      if (PHASE == 3) lds[lane * LDS_STRIDE + t] = lastout;
      float xin2 = lds[lane * LDS_STRIDE + t + 1];
      STEP(yB, yA, uB, uA, xin2)
      if (PHASE == 3) lds[lane * LDS_STRIDE + t + 1] = lastout;
    }
    if (PHASE == 3) {
      __syncthreads();
      // Coalesced stage-out (in-place LDS reuse).
#pragma unroll
      for (int r = 0; r < 64; ++r)
        out[(size_t)r * T + t0 + lane] = lds[r * LDS_STRIDE + lane];
    }
  }

  if (PHASE == 1) {
    // After 256 steps (even), y1 lives in yA, y2 in yB. Coalesced z write.
#pragma unroll
    for (int k = 0; k < K; ++k) {
      z[(b * 16 + k) * 64 + lane] = yA[k];
      z[(b * 16 + 8 + k) * 64 + lane] = yB[k];
    }
  }
  (void)lastout;
}

extern "C" void kernel_launch(void* const* d_in, const int* in_sizes, int n_in,
                              void* d_out, int out_size, void* d_ws,
                              size_t ws_size, hipStream_t stream) {
  const float* x = (const float*)d_in[0];     // [C, T]
  const float* sos = (const float*)d_in[1];   // [K, 6]
  const float* sx = (const float*)d_in[2];    // [K, C, 2]
  const float* sy = (const float*)d_in[3];    // [K, C, 2]
  float* out = (float*)d_out;                 // [C, T]
  float* z = (float*)d_ws;                    // [B, 16, C] block end states

  sos_kernel<1><<<B, 64, 0, stream>>>(x, sos, sx, sy, z, out);
  sos_kernel<3><<<B, 64, 0, stream>>>(x, sos, sx, sy, z, out);
}

// Round 2
// 160.931 us; speedup vs baseline: 1.0534x; 1.0534x over previous
//
#include <hip/hip_runtime.h>

#define C 64
#define T 262144
#define K 8
#define L 256
#define B (T / L)      // 1024 time blocks
#define TT 64          // time steps per LDS chunk
#define NCH (L / TT)   // 4 chunks per block
#define STRIDE 65      // LDS row stride in words; 65%32=1 -> 2-way max (free)

// Async global->LDS: each lane loads gp[lane] (4B), lands at ldsbase[lane].
__device__ __forceinline__ void async_ld(const float* gp, float* ldsbase) {
  __builtin_amdgcn_global_load_lds(
      (const __attribute__((address_space(1))) void*)gp,
      (__attribute__((address_space(3))) void*)ldsbase, 4, 0, 0);
}

// One cascade time-step (identical math/order to R1 — passed at 4.9e-4).
#define STEP(Y1, Y2, U1, U2, XIN)                                            \
  {                                                                          \
    float tkv[K];                                                            \
    tkv[0] = fmaf(b1c[0], U1,                                                \
             fmaf(b2c[0], U2, fmaf(na1[0], Y1[0], na2[0] * Y2[0])));         \
    _Pragma("unroll")                                                        \
    for (int k = 1; k < K; ++k)                                              \
      tkv[k] = fmaf(b1c[k], Y1[k - 1],                                       \
               fmaf(b2c[k], Y2[k - 1],                                       \
               fmaf(na1[k], Y1[k], na2[k] * Y2[k])));                        \
    float o = fmaf(b0c[0], (XIN), tkv[0]);                                   \
    U2 = (XIN);                                                              \
    _Pragma("unroll")                                                        \
    for (int k = 1; k < K; ++k) {                                            \
      float o2 = fmaf(b0c[k], o, tkv[k]);                                    \
      Y2[k - 1] = o;                                                         \
      o = o2;                                                                \
    }                                                                        \
    Y2[K - 1] = o;                                                           \
    lastout = o;                                                             \
  }

// PHASE 1: run block from zero y-state (true x taps), record end state z[b].
//          Reads x only — no out traffic. Grid = B-1 (z[B-1] unused).
// PHASE 2: run block from z[b-1] (true state to ~1e-8), write out. Grid = B.
// One wave per block; lane = channel. Double-buffered async staging.
template <int PHASE>
__global__ __launch_bounds__(64) void sos_kernel(
    const float* __restrict__ x, const float* __restrict__ sos,
    const float* __restrict__ sx, const float* __restrict__ sy,
    float* __restrict__ z, float* __restrict__ out) {
  __shared__ float lbuf[2][64 * STRIDE];
  const int b = blockIdx.x;
  const int lane = threadIdx.x;  // = channel

  // Wave-uniform coefficients (compiler -> SGPRs). sos row: b0,b1,b2,1,a1,a2
  float b0c[K], b1c[K], b2c[K], na1[K], na2[K];
#pragma unroll
  for (int k = 0; k < K; ++k) {
    b0c[k] = sos[k * 6 + 0];
    b1c[k] = sos[k * 6 + 1];
    b2c[k] = sos[k * 6 + 2];
    na1[k] = -sos[k * 6 + 4];
    na2[k] = -sos[k * 6 + 5];
  }

  // State init. yA/yB swap y1/y2 roles each step; uA/uB = section-0 x taps.
  float yA[K], yB[K], uA, uB;
  const int t0b = b * L;
  if (b == 0) {
    uA = sx[lane * 2 + 0];
    uB = sx[lane * 2 + 1];
#pragma unroll
    for (int k = 0; k < K; ++k) {
      yA[k] = sy[(k * 64 + lane) * 2 + 0];
      yB[k] = sy[(k * 64 + lane) * 2 + 1];
    }
  } else {
    uA = x[(size_t)lane * T + t0b - 1];  // true input history
    uB = x[(size_t)lane * T + t0b - 2];
    if (PHASE == 1) {
#pragma unroll
      for (int k = 0; k < K; ++k) { yA[k] = 0.f; yB[k] = 0.f; }
    } else {
#pragma unroll
      for (int k = 0; k < K; ++k) {
        yA[k] = z[((b - 1) * 16 + k) * 64 + lane];
        yB[k] = z[((b - 1) * 16 + 8 + k) * 64 + lane];
      }
    }
  }

  // Prefetch chunk 0 (async; barrier at loop top drains it).
#pragma unroll
  for (int r = 0; r < 64; ++r)
    async_ld(x + (size_t)r * T + t0b + lane, &lbuf[0][r * STRIDE]);

  float lastout = 0.f;
  for (int ch = 0; ch < NCH; ++ch) {
    __syncthreads();  // chunk ch loads visible; prior LDS reads done
    if (ch + 1 < NCH) {
      const int t0n = t0b + (ch + 1) * TT;
      float* nbuf = lbuf[(ch + 1) & 1];
#pragma unroll
      for (int r = 0; r < 64; ++r)
        async_ld(x + (size_t)r * T + t0n + lane, &nbuf[r * STRIDE]);
    }
    float* buf = lbuf[ch & 1];
    float* myrow = &buf[lane * STRIDE];

    // Software-pipelined groups of 8 steps (xg0/xg1 rotate).
    float xg0[8], xg1[8];
#pragma unroll
    for (int j = 0; j < 8; ++j) xg0[j] = myrow[j];
    for (int gg = 0; gg < TT / 16; ++gg) {
      const int tb = gg * 16;
#pragma unroll
      for (int j = 0; j < 8; ++j) xg1[j] = myrow[tb + 8 + j];
#pragma unroll
      for (int j = 0; j < 8; j += 2) {
        STEP(yA, yB, uA, uB, xg0[j])
        if (PHASE == 2) myrow[tb + j] = lastout;
        STEP(yB, yA, uB, uA, xg0[j + 1])
        if (PHASE == 2) myrow[tb + j + 1] = lastout;
      }
      if (gg + 1 < TT / 16) {
#pragma unroll
        for (int j = 0; j < 8; ++j) xg0[j] = myrow[tb + 16 + j];
      }
#pragma unroll
      for (int j = 0; j < 8; j += 2) {
        STEP(yA, yB, uA, uB, xg1[j])
        if (PHASE == 2) myrow[tb + 8 + j] = lastout;
        STEP(yB, yA, uB, uA, xg1[j + 1])
        if (PHASE == 2) myrow[tb + 8 + j + 1] = lastout;
      }
    }

    if (PHASE == 2) {
      __syncthreads();  // cross-lane: stage-out reads other lanes' rows
      const int tg = t0b + ch * TT;
#pragma unroll 8
      for (int r = 0; r < 64; ++r)
        out[(size_t)r * T + tg + lane] = buf[r * STRIDE + lane];
    }
  }

  if (PHASE == 1) {
    // 256 steps (even): y1 in yA, y2 in yB. Coalesced z write.
#pragma unroll
    for (int k = 0; k < K; ++k) {
      z[(b * 16 + k) * 64 + lane] = yA[k];
      z[(b * 16 + 8 + k) * 64 + lane] = yB[k];
    }
  }
  (void)lastout;
}

extern "C" void kernel_launch(void* const* d_in, const int* in_sizes, int n_in,
                              void* d_out, int out_size, void* d_ws,
                              size_t ws_size, hipStream_t stream) {
  const float* x = (const float*)d_in[0];    // [C, T]
  const float* sos = (const float*)d_in[1];  // [K, 6]
  const float* sx = (const float*)d_in[2];   // [K, C, 2]
  const float* sy = (const float*)d_in[3];   // [K, C, 2]
  float* out = (float*)d_out;                // [C, T]
  float* z = (float*)d_ws;                   // [B-1, 16, C] block end states

  sos_kernel<1><<<B - 1, 64, 0, stream>>>(x, sos, sx, sy, z, out);
  sos_kernel<2><<<B, 64, 0, stream>>>(x, sos, sx, sy, z, out);
}